// Round 5
// baseline (373.457 us; speedup 1.0000x reference)
//
#include <hip/hip_runtime.h>
#include <cstddef>

static constexpr int CB = 64;    // batch
static constexpr int CN = 512;   // nodes
static constexpr int CD = 256;   // node model dim
static constexpr int CE = 128;   // edge model dim
static constexpr int CIT = 20;   // sinkhorn iterations

typedef _Float16 half_t;
typedef __attribute__((ext_vector_type(8))) _Float16 v8h;
typedef __attribute__((ext_vector_type(4))) _Float16 v4h;
typedef __attribute__((ext_vector_type(4))) float v4f;

// ---------------------------------------------------------------------------
// LLC-coherent 16B ops (validated R2 protocol, 158 µs): bypass L1/L2 to the
// coherence point; NO fences, NO cache-maintenance ops (R1 showed
// release/acquire => buffer_wbl2/inv storms, +83 µs/iter). Correctness:
// payload-as-flag sentinel (-1 precleared, strictly-positive payload); each
// 4B word flips monotonically once; reader accepts a float4 only when all 4
// words are positive, so 16B tearing is harmless.
// Protocol ledger: R0 scalar atomics 160.7 | R2 this 158.4 | R3 +L2 channel
// 173 (L2 path never fires) | R4 +XCD remap 190 (co-location assumption
// false). Exchange mechanics are exhausted; do not re-add channels/remaps.
// ---------------------------------------------------------------------------
__device__ __forceinline__ void llc_store4(v4f* p, v4f v) {
  asm volatile("global_store_dwordx4 %0, %1, off sc0 sc1"
               :: "v"(p), "v"(v) : "memory");
}
__device__ __forceinline__ void llc_load3x4(const v4f* p0, const v4f* p1,
                                            const v4f* p2,
                                            v4f& a, v4f& b, v4f& c) {
  asm volatile("global_load_dwordx4 %0, %3, off sc0 sc1\n\t"
               "global_load_dwordx4 %1, %4, off sc0 sc1\n\t"
               "global_load_dwordx4 %2, %5, off sc0 sc1\n\t"
               "s_waitcnt vmcnt(0)"
               : "=&v"(a), "=&v"(b), "=&v"(c)
               : "v"(p0), "v"(p1), "v"(p2)
               : "memory");
}
__device__ __forceinline__ bool allpos(v4f v) {
  return v[0] > 0.0f && v[1] > 0.0f && v[2] > 0.0f && v[3] > 0.0f;
}

// ---------------------------------------------------------------------------
// prep_both, MERGED (this round's bet: kill the k0 dispatch, ~30-50 µs/gap):
//   phase 0: grid-stride preclear of the 10.5 MB dataflow slots to -1
//            (plain stores; kernel-boundary flush makes them visible to
//            fused_reg's sc0sc1 polls — same guarantee k0 provided)
//   phase 1: B-path blocks detect mask dtype locally (same 32 KB window +
//            decision logic as the old k0 block 0; LLC-hot after 1st block)
//   phase 2: X staging (unchanged)
//   phase 3: GEMM with W fragments converted INLINE from the LLC-resident
//            fp32 W_a/W_b (8 strided dword loads + cvt per fragment replaces
//            the old precomputed-WaF v8h load; hidden under MFMAs)
// Blocks 0..511 = A-path (x = out_emb + pos, w_aff folded); 512..1023 =
// B-path (x = mask ? pad : in_emb). out fp16 row-major, K=256.
// ---------------------------------------------------------------------------
__global__ __launch_bounds__(256) void prep_both(
    const float* __restrict__ out_emb, const float* __restrict__ pos,
    const float* __restrict__ in_emb, const float* __restrict__ pad,
    const void* __restrict__ maskp,
    const float* __restrict__ W_a, const float* __restrict__ W_b,
    const float* __restrict__ w_aff,
    half_t* __restrict__ A_h, half_t* __restrict__ Bm_h,
    float4* __restrict__ clearp, int nclear4) {
  __shared__ half_t Xs[64][264];   // 33.8 KB
  __shared__ int cnt[5];
  const int tid = threadIdx.x;

  // ---- phase 0: cooperative preclear (grid-stride over 1024x256 threads)
  {
    const int gs = 1024 * 256;
    for (int idx = blockIdx.x * 256 + tid; idx < nclear4; idx += gs)
      clearp[idx] = make_float4(-1.0f, -1.0f, -1.0f, -1.0f);
  }

  const int wv = tid >> 6, ln = tid & 63;
  const bool isA = blockIdx.x < 512;
  const int row0 = (isA ? blockIdx.x : blockIdx.x - 512) * 64;
  const float* X = isA ? out_emb : in_emb;
  const float* extra = isA ? pos : pad;
  half_t* out = isA ? A_h : Bm_h;

  // ---- phase 1: local mask dtype detection (B-path blocks only) ----
  // flag: 0=int32, 1=uint8(bool), 2=float32, 3=int64
  int flag = 0;
  if (!isA) {
    if (tid < 5) cnt[tid] = 0;
    __syncthreads();
    const unsigned char* p = (const unsigned char*)maskp;
    int l0 = 0, l1 = 0, l2 = 0, l3 = 0, l4 = 0;
    const int base = tid * 128;
    for (int k = 0; k < 128; ++k) {
      const int off = base + k;
      if (p[off]) {
        const int m4 = off & 3;
        if (m4 == 1) l1++;
        else if (m4 == 2) l2++;
        else if (m4 == 3) l3++;
        else if ((off & 7) == 4) l4++;
        else l0++;
      }
    }
    if (l0) atomicAdd(&cnt[0], 1);
    if (l1) atomicAdd(&cnt[1], 1);
    if (l2) atomicAdd(&cnt[2], 1);
    if (l3) atomicAdd(&cnt[3], 1);
    if (l4) atomicAdd(&cnt[4], 1);
    __syncthreads();
    if (cnt[1]) flag = 1;
    else if (cnt[2] || cnt[3]) flag = 2;
    else if (cnt[4]) flag = 0;
    else if (cnt[0]) flag = 3;
    else flag = 1;
  }

  // ---- phase 2: X staging ----
#pragma unroll 4
  for (int it = 0; it < 16; ++it) {
    const int r = it * 4 + wv;
    const int row = row0 + r;
    const int c = ln * 4;
    float4 x4;
    if (isA) {
      x4 = *(const float4*)&X[(size_t)row * CD + c];
      const int i = row & (CN - 1);
      const float4 p4 = *(const float4*)&extra[(size_t)i * CD + c];
      x4.x += p4.x; x4.y += p4.y; x4.z += p4.z; x4.w += p4.w;
    } else {
      bool m;
      if (flag == 1)      m = ((const unsigned char*)maskp)[row] != 0;
      else if (flag == 2) m = ((const float*)maskp)[row] != 0.0f;
      else if (flag == 3) m = ((const long long*)maskp)[row] != 0;
      else                m = ((const int*)maskp)[row] != 0;
      if (m) x4 = *(const float4*)&extra[c];
      else   x4 = *(const float4*)&X[(size_t)row * CD + c];
    }
    v4h hv;
    hv[0] = (half_t)x4.x; hv[1] = (half_t)x4.y;
    hv[2] = (half_t)x4.z; hv[3] = (half_t)x4.w;
    *(v4h*)&Xs[r][c] = hv;
  }
  __syncthreads();

  // ---- phase 3: GEMM with inline W fragment conversion ----
  const int q = ln >> 4, l = ln & 15;
  v8h af[8];
#pragma unroll
  for (int kf = 0; kf < 8; ++kf)
    af[kf] = *(v8h*)&Xs[wv * 16 + l][kf * 32 + q * 8];
  const float* W = isA ? W_a : W_b;
  v4f acc[8] = {};
#pragma unroll
  for (int nn = 0; nn < 8; ++nn) {
    const int col = nn * 16 + l;
    const float scale = isA ? w_aff[col] : 1.0f;
    v8h bf[8];
#pragma unroll
    for (int kf = 0; kf < 8; ++kf) {
      const float* Wp = &W[(size_t)(kf * 32 + q * 8) * CE + col];
      v8h hv;
#pragma unroll
      for (int j = 0; j < 8; ++j)
        hv[j] = (half_t)(Wp[(size_t)j * CE] * scale);
      bf[kf] = hv;
    }
#pragma unroll
    for (int kf = 0; kf < 8; ++kf)
      acc[nn] = __builtin_amdgcn_mfma_f32_16x16x32_f16(af[kf], bf[kf], acc[nn], 0, 0, 0);
  }
#pragma unroll
  for (int nn = 0; nn < 8; ++nn)
#pragma unroll
    for (int g = 0; g < 4; ++g) {
      const int row = row0 + wv * 16 + q * 4 + g;
      out[(size_t)row * CE + nn * 16 + l] = (half_t)acc[nn][g];
    }
}

// ---------------------------------------------------------------------------
// fused_reg: block = (batch b, 128-row slab), 512 thr = 8 waves, grid 256.
// R2-validated artifact (158 µs): default block mapping, single LLC sentinel
// channel, 128-thread 16B exchange. Only delta vs R2: w1/w2 in ONE shared
// array with w2 at +544 halfs (+16 banks) — kills the 5.3M 2-way bank-alias
// conflicts (validated 57K in R3/R4).
// ---------------------------------------------------------------------------
__global__ __launch_bounds__(512, 2) void fused_reg(
    const half_t* __restrict__ A_h, const half_t* __restrict__ B_h,
    const float* __restrict__ baff, float* __restrict__ P,
    float* __restrict__ partInit, float* __restrict__ partIter) {
  __shared__ float comb2[8][512][2];           // 32 KB, [wave][col][s1|s2]
  __shared__ __align__(16) float2 w12[512];    // {0.5*v*csinv, v} (finalize)
  __shared__ __align__(16) float QsL[512];     // per-col publish staging
  __shared__ __align__(16) v4f csinv4[128];    // 1/colsum, 4 cols per slot
  __shared__ __align__(16) half_t wAll[1056];  // w1 @0, w2 @544 (+16 banks)

  const int tid = threadIdx.x;
  const int wv = tid >> 6, ln = tid & 63;
  const int q = ln >> 4, l = ln & 15;
  const int b = blockIdx.x & 63;
  const int slab = blockIdx.x >> 6;
  const int i0 = slab * 128;
  const float bbs = *baff - 2.7725887f;   // fold 2^-4 scale into exp

  int rs3[3];   // the 3 remote slabs (static-indexed only)
  {
    int k = 0;
#pragma unroll
    for (int sl = 0; sl < 4; ++sl)
      if (sl != slab) rs3[k++] = sl;
  }

  // ---- GEMM: E and E^T tiles, fp16 MFMA, K=128 ----
  v8h af[4];
  {
    const half_t* Arow = &A_h[((size_t)b * CN + i0 + wv * 16 + l) * CE];
#pragma unroll
    for (int ki = 0; ki < 4; ++ki)
      af[ki] = *(const v8h*)&Arow[ki * 32 + q * 8];
  }
  v4h eh[32];    // E[row = wv*16 + q*4+g][col = ct*16 + l]
  v4h ehT[32];   // E[row = wv*16 + l][col = ct*16 + q*4+g]
  const half_t* Bbase = &B_h[(size_t)b * CN * CE];
#pragma unroll
  for (int ct = 0; ct < 32; ++ct) {
    v8h bf[4];
    const half_t* Brow = &Bbase[(size_t)(ct * 16 + l) * CE];
#pragma unroll
    for (int ki = 0; ki < 4; ++ki)
      bf[ki] = *(const v8h*)&Brow[ki * 32 + q * 8];
    v4f acc = {}, accT = {};
#pragma unroll
    for (int ki = 0; ki < 4; ++ki) {
      acc  = __builtin_amdgcn_mfma_f32_16x16x32_f16(af[ki], bf[ki], acc,  0, 0, 0);
      accT = __builtin_amdgcn_mfma_f32_16x16x32_f16(bf[ki], af[ki], accT, 0, 0, 0);
    }
#pragma unroll
    for (int g = 0; g < 4; ++g) {
      eh[ct][g]  = (half_t)__expf(acc[g]  + bbs);
      ehT[ct][g] = (half_t)__expf(accT[g] + bbs);
    }
  }

  // ---- init sums via MFMA (ones fragment) ----
  v4h ones;
  ones[0] = (half_t)1.0f; ones[1] = (half_t)1.0f;
  ones[2] = (half_t)1.0f; ones[3] = (half_t)1.0f;
  v4f rowacc0 = {}, rowacc1 = {};
#pragma unroll
  for (int ct = 0; ct < 32; ct += 2) {
    const v4f c0 = __builtin_amdgcn_mfma_f32_16x16x16f16(ones, eh[ct], (v4f){}, 0, 0, 0);
    const v4f c1 = __builtin_amdgcn_mfma_f32_16x16x16f16(ones, eh[ct + 1], (v4f){}, 0, 0, 0);
    if (ln < 16) {
      comb2[wv][ct * 16 + ln][0] = c0[0];
      comb2[wv][(ct + 1) * 16 + ln][0] = c1[0];
    }
    rowacc0 = __builtin_amdgcn_mfma_f32_16x16x16f16(ones, ehT[ct],     rowacc0, 0, 0, 0);
    rowacc1 = __builtin_amdgcn_mfma_f32_16x16x16f16(ones, ehT[ct + 1], rowacc1, 0, 0, 0);
  }
  const float rowtot = rowacc0[0] + rowacc1[0];
  float rv[4];   // 1/rowsum for this lane's 4 rows (q*4+g)
#pragma unroll
  for (int g = 0; g < 4; ++g)
    rv[g] = 1.0f / __shfl(rowtot, q * 4 + g);
  __syncthreads();

  // ---- init exchange: sentinel dataflow, 16B ops on 128 threads ----
  {
    float S = 0.0f;
#pragma unroll
    for (int w = 0; w < 8; ++w) S += comb2[w][tid][0];
    QsL[tid] = S;                 // colsum staging (strictly positive)
  }
  __syncthreads();
  if (tid < 128) {
    const v4f s4 = *(const v4f*)&QsL[tid * 4];
    v4f* pi4 = (v4f*)partInit + (size_t)b * 4 * 128;
    llc_store4(&pi4[slab * 128 + tid], s4);
    const v4f* q0 = &pi4[rs3[0] * 128 + tid];
    const v4f* q1 = &pi4[rs3[1] * 128 + tid];
    const v4f* q2 = &pi4[rs3[2] * 128 + tid];
    v4f r0, r1, r2;
    while (true) {
      llc_load3x4(q0, q1, q2, r0, r1, r2);
      if (allpos(r0) && allpos(r1) && allpos(r2)) break;
      __builtin_amdgcn_s_sleep(1);
    }
    const v4f T = s4 + r0 + r1 + r2;
    v4f ci;
    v4h w1v, w2v;
#pragma unroll
    for (int j = 0; j < 4; ++j) {
      ci[j] = 1.0f / T[j];
      w1v[j] = (half_t)(0.5f * ci[j]);
      w2v[j] = (half_t)1.0f;
    }
    csinv4[tid] = ci;
    *(v4h*)&wAll[tid * 4] = w1v;
    *(v4h*)&wAll[544 + tid * 4] = w2v;
  }
  __syncthreads();
  const float ci0 = ((const float*)csinv4)[tid];   // 1/colsum for column tid

  // ---- 20 sinkhorn iterations (packed MFMA passes) ----
  const half_t* wbase = (l == 1) ? (wAll + 544) : wAll;   // row0=w1, row1=w2
  float u_[4], uri[4];
  for (int t = 0; t < CIT; ++t) {
    __syncthreads();   // wAll ready
    // pass 1: row dots via E^T tiles; ONE mfma per ct (rows 0/1 = w1/w2)
    v4f Pe = {}, Po = {};
#pragma unroll
    for (int ct = 0; ct < 32; ct += 2) {
      const v4h wf0 = *(const v4h*)&wbase[ct * 16 + q * 4];
      const v4h wf1 = *(const v4h*)&wbase[(ct + 1) * 16 + q * 4];
      Pe = __builtin_amdgcn_mfma_f32_16x16x16f16(wf0, ehT[ct],     Pe, 0, 0, 0);
      Po = __builtin_amdgcn_mfma_f32_16x16x16f16(wf1, ehT[ct + 1], Po, 0, 0, 0);
    }
    const float Prow1 = Pe[0] + Po[0];   // w1-weighted row dot (C row 0)
    const float Prow2 = Pe[1] + Po[1];   // w2-weighted row dot (C row 1)
    // redistribute p[row l&15] -> this lane's rows q*4+g; compute u
    v4h u_h, uri_h;
#pragma unroll
    for (int g = 0; g < 4; ++g) {
      const float p1 = __shfl(Prow1, q * 4 + g);
      const float p2 = __shfl(Prow2, q * 4 + g);
      u_[g] = 1.0f / (p1 + 0.5f * rv[g] * p2);
      uri[g] = u_[g] * rv[g];
      u_h[g] = (half_t)u_[g];
      uri_h[g] = (half_t)uri[g];
    }
    // pass 2: column partials via E tiles; rows 0/1 of A = u/uri packed
    const v4h a2 = (l == 1) ? uri_h : u_h;
#pragma unroll
    for (int ct = 0; ct < 32; ++ct) {
      const v4f s = __builtin_amdgcn_mfma_f32_16x16x16f16(a2, eh[ct], (v4f){}, 0, 0, 0);
      if (ln < 16)
        *(float2*)&comb2[wv][ct * 16 + ln][0] = make_float2(s[0], s[1]);
    }
    __syncthreads();
    // cross-wave reduce (all 512 threads) + stage Q = 0.5*(ci*S1 + S2)
    {
      float S1 = 0.0f, S2 = 0.0f;
#pragma unroll
      for (int w = 0; w < 8; ++w) {
        const float2 c2v = *(const float2*)&comb2[w][tid][0];
        S1 += c2v.x;
        S2 += c2v.y;
      }
      QsL[tid] = 0.5f * fmaf(ci0, S1, S2);   // strictly positive
    }
    __syncthreads();
    // 128-thread 16B sentinel exchange + w update
    if (tid < 128) {
      const v4f Q4 = *(const v4f*)&QsL[tid * 4];
      v4f* pr4 = (v4f*)partIter + (((size_t)t * 64 + b) * 4) * 128;
      llc_store4(&pr4[slab * 128 + tid], Q4);
      const v4f* q0 = &pr4[rs3[0] * 128 + tid];
      const v4f* q1 = &pr4[rs3[1] * 128 + tid];
      const v4f* q2 = &pr4[rs3[2] * 128 + tid];
      v4f r0, r1, r2;
      while (true) {
        llc_load3x4(q0, q1, q2, r0, r1, r2);
        if (allpos(r0) && allpos(r1) && allpos(r2)) break;
        __builtin_amdgcn_s_sleep(1);
      }
      const v4f tot = Q4 + r0 + r1 + r2;
      const v4f ci = csinv4[tid];
      v4h w1v, w2v;
#pragma unroll
      for (int j = 0; j < 4; ++j) {
        const float vv = 1.0f / tot[j];
        w1v[j] = (half_t)(0.5f * vv * ci[j]);
        w2v[j] = (half_t)vv;
        if (t == CIT - 1)
          w12[tid * 4 + j] = make_float2(0.5f * vv * ci[j], vv);
      }
      *(v4h*)&wAll[tid * 4] = w1v;
      *(v4h*)&wAll[544 + tid * 4] = w2v;
    }
  }

  // ---- finalize: P = E * u_i * v_j * (0.5*csinv_j + 0.5*rinv_i) ----
  __syncthreads();
  float* Pb = &P[((size_t)b * CN + i0 + wv * 16 + q * 4) * CN];
#pragma unroll
  for (int ct = 0; ct < 32; ++ct) {
    const float2 w = w12[ct * 16 + l];
    const float c1 = w.x;
    const float c2 = 0.5f * w.y;
#pragma unroll
    for (int g = 0; g < 4; ++g) {
      const float e = (float)eh[ct][g];
      Pb[(size_t)g * CN + ct * 16 + l] = e * fmaf(u_[g], c1, uri[g] * c2);
    }
  }
}

// ---------------------------------------------------------------------------
extern "C" void kernel_launch(void* const* d_in, const int* in_sizes, int n_in,
                              void* d_out, int out_size, void* d_ws, size_t ws_size,
                              hipStream_t stream) {
  const float* in_emb  = (const float*)d_in[0];
  const void*  mask    = d_in[1];
  const float* out_emb = (const float*)d_in[2];
  const float* pad     = (const float*)d_in[3];
  const float* pos     = (const float*)d_in[4];
  const float* W_a     = (const float*)d_in[5];
  const float* W_b     = (const float*)d_in[6];
  const float* w_aff   = (const float*)d_in[7];
  const float* b_aff   = (const float*)d_in[8];
  float* P = (float*)d_out;

  char* ws = (char*)d_ws;
  const size_t MB = 1024 * 1024;
  const size_t KB = 1024;
  half_t* A_h  = (half_t*)ws;                              // 8 MB
  half_t* Bm_h = (half_t*)(ws + 8 * MB);                   // 8 MB
  float* partInit = (float*)(ws + 16 * MB + 256 * KB);     // 512 KB
  float* partIter = (float*)(ws + 16 * MB + 768 * KB);     // 10 MB

  // dataflow slots: 10.5 MB contiguous starting at partInit, sentinel -1,
  // cleared cooperatively by prep_both phase 0 (kernel-boundary flush
  // guarantees visibility to fused_reg — same as the old k0 path).
  const int nclear4 = (512 * 1024 + 10 * 1024 * 1024) / 16;   // 688,128 float4

  prep_both<<<dim3(1024), dim3(256), 0, stream>>>(
      out_emb, pos, in_emb, pad, mask, W_a, W_b, w_aff,
      A_h, Bm_h, (float4*)partInit, nclear4);
  fused_reg<<<dim3(256), dim3(512), 0, stream>>>(
      A_h, Bm_h, b_aff, P, partInit, partIter);
}

// Round 6
// 306.239 us; speedup vs baseline: 1.2195x; 1.2195x over previous
//
#include <hip/hip_runtime.h>
#include <cstddef>

static constexpr int CB = 64;    // batch
static constexpr int CN = 512;   // nodes
static constexpr int CD = 256;   // node model dim
static constexpr int CE = 128;   // edge model dim
static constexpr int CIT = 20;   // sinkhorn iterations

typedef _Float16 half_t;
typedef __attribute__((ext_vector_type(8))) _Float16 v8h;
typedef __attribute__((ext_vector_type(4))) _Float16 v4h;
typedef __attribute__((ext_vector_type(4))) float v4f;

// ---------------------------------------------------------------------------
// LLC-coherent ops (validated R2 protocol): bypass L1/L2 to the coherence
// point; NO fences, NO cache-maintenance (R1: release/acquire =>
// buffer_wbl2/inv storms). Sentinel: -1 precleared, strictly-positive payload,
// per-4B-word monotone flip => tearing harmless.
// Protocol ledger: R0 scalar atomics 160.7 | R2 16B-sentinel 158.4 | R3 +L2
// channel 173 | R4 +XCD remap 190. Exchange mechanics exhausted — unchanged.
// NEW this round (B handoff): sc0sc1 data stores -> per-wave vmcnt drain (at
// __syncthreads) -> ONE marker store/block -> peers poll 3 markers -> plain
// cached B reads (safe: Bm lines first-touched after markers this launch;
// kernel-boundary invalidation covers prior launches).
// ---------------------------------------------------------------------------
__device__ __forceinline__ void llc_store4(v4f* p, v4f v) {
  asm volatile("global_store_dwordx4 %0, %1, off sc0 sc1"
               :: "v"(p), "v"(v) : "memory");
}
__device__ __forceinline__ void llc_storef(float* p, float v) {
  asm volatile("global_store_dword %0, %1, off sc0 sc1"
               :: "v"(p), "v"(v) : "memory");
}
__device__ __forceinline__ void llc_load3x4(const v4f* p0, const v4f* p1,
                                            const v4f* p2,
                                            v4f& a, v4f& b, v4f& c) {
  asm volatile("global_load_dwordx4 %0, %3, off sc0 sc1\n\t"
               "global_load_dwordx4 %1, %4, off sc0 sc1\n\t"
               "global_load_dwordx4 %2, %5, off sc0 sc1\n\t"
               "s_waitcnt vmcnt(0)"
               : "=&v"(a), "=&v"(b), "=&v"(c)
               : "v"(p0), "v"(p1), "v"(p2)
               : "memory");
}
__device__ __forceinline__ void llc_load3f(const float* p0, const float* p1,
                                           const float* p2,
                                           float& a, float& b, float& c) {
  asm volatile("global_load_dword %0, %3, off sc0 sc1\n\t"
               "global_load_dword %1, %4, off sc0 sc1\n\t"
               "global_load_dword %2, %5, off sc0 sc1\n\t"
               "s_waitcnt vmcnt(0)"
               : "=&v"(a), "=&v"(b), "=&v"(c)
               : "v"(p0), "v"(p1), "v"(p2)
               : "memory");
}
__device__ __forceinline__ bool allpos(v4f v) {
  return v[0] > 0.0f && v[1] > 0.0f && v[2] > 0.0f && v[3] > 0.0f;
}

// ---------------------------------------------------------------------------
// k0 (R2-validated, unchanged logic): block 0 = mask dtype detect; block 1 =
// idle; 2..9 = W_a -> fp16 B-fragments (w_aff folded); 10..17 = W_b;
// blocks >= 18 preclear the sentinel region (partInit + partIter + markers)
// to -1.0f. flag: 0=int32, 1=uint8(bool), 2=float32, 3=int64
// ---------------------------------------------------------------------------
__global__ __launch_bounds__(512) void k0_init(
    const void* __restrict__ mask, int* __restrict__ flag,
    const float* __restrict__ W_a, const float* __restrict__ W_b,
    const float* __restrict__ w_aff,
    half_t* __restrict__ WaF, half_t* __restrict__ WbF,
    float4* __restrict__ clearp, int nclear4) {
  const int tid = threadIdx.x;
  const int blk = blockIdx.x;
  if (blk == 1) return;
  if (blk >= 18) {
    const int idx = (blk - 18) * 512 + tid;
    if (idx < nclear4)
      clearp[idx] = make_float4(-1.0f, -1.0f, -1.0f, -1.0f);
    return;
  }
  if (blk >= 2) {
    const bool is_a = (blk < 10);
    const float* W = is_a ? W_a : W_b;
    half_t* WF = is_a ? WaF : WbF;
    const int e = (blk - (is_a ? 2 : 10)) * 512 + tid;   // 0..4095
    const int fB = e >> 6, lane = e & 63;
    const int nn = fB >> 3, kf = fB & 7;
    const int col = nn * 16 + (lane & 15);
    const int q = lane >> 4;
    const float scale = is_a ? w_aff[col] : 1.0f;
    v8h hv;
#pragma unroll
    for (int j = 0; j < 8; ++j) {
      const int k = kf * 32 + q * 8 + j;
      hv[j] = (half_t)(W[(size_t)k * CE + col] * scale);
    }
    *(v8h*)&WF[(size_t)e * 8] = hv;
    return;
  }
  // blk == 0: mask dtype detection over first 32768 bytes
  __shared__ int cnt[5];
  if (tid < 5) cnt[tid] = 0;
  __syncthreads();
  const unsigned char* p = (const unsigned char*)mask;
  int l0 = 0, l1 = 0, l2 = 0, l3 = 0, l4 = 0;
  const int base = tid * 64;
  for (int k = 0; k < 64; ++k) {
    const int off = base + k;
    if (p[off]) {
      const int m4 = off & 3;
      if (m4 == 1) l1++;
      else if (m4 == 2) l2++;
      else if (m4 == 3) l3++;
      else if ((off & 7) == 4) l4++;
      else l0++;
    }
  }
  if (l0) atomicAdd(&cnt[0], 1);
  if (l1) atomicAdd(&cnt[1], 1);
  if (l2) atomicAdd(&cnt[2], 1);
  if (l3) atomicAdd(&cnt[3], 1);
  if (l4) atomicAdd(&cnt[4], 1);
  __syncthreads();
  if (tid == 0) {
    int f;
    if (cnt[1]) f = 1;
    else if (cnt[2] || cnt[3]) f = 2;
    else if (cnt[4]) f = 0;
    else if (cnt[0]) f = 3;
    else f = 1;
    *flag = f;
  }
}

// ---------------------------------------------------------------------------
// mega: prep + sinkhorn in ONE dispatch. Block = (b, slab). Phases:
//  P1 A-prep (block-local): xf from global fp32 (out_emb+pos), GEMM vs WaF,
//     result -> LDS bounce [128][136] -> read back as af fragments (no A_h).
//  P2 B-prep: xf from global (mask?pad:in_emb), GEMM vs WbF, bounce -> 
//     coalesced sc0sc1 stores to Bm -> barrier(drains vmcnt) -> marker.
//  P3 poll 3 peer markers (sentinel protocol) -> E-GEMM with PLAIN cached
//     B reads (first-touch-after-marker argument above).
//  P4 sinkhorn: byte-level R2 artifact (158 µs validated) + wAll bank fix.
// Grid 256 = 1 block/CU => co-residency (same invariant the sinkhorn needs).
// ---------------------------------------------------------------------------
__global__ __launch_bounds__(512, 2) void mega(
    const float* __restrict__ out_emb, const float* __restrict__ pos,
    const float* __restrict__ in_emb, const float* __restrict__ pad,
    const void* __restrict__ maskp, const int* __restrict__ flagp,
    const half_t* __restrict__ WaF, const half_t* __restrict__ WbF,
    half_t* __restrict__ Bm_h,
    const float* __restrict__ baff, float* __restrict__ P,
    float* __restrict__ partInit, float* __restrict__ partIter,
    float* __restrict__ markers) {
  // smem2: A/B bounce [128][136] halfs (34816 B), later aliased as comb2
  __shared__ __align__(16) char smem2[34816];
  __shared__ __align__(16) float2 w12[512];    // {0.5*v*csinv, v} (finalize)
  __shared__ __align__(16) float QsL[512];     // per-col publish staging
  __shared__ __align__(16) v4f csinv4[128];    // 1/colsum, 4 cols per slot
  __shared__ __align__(16) half_t wAll[1056];  // w1 @0, w2 @544 (+16 banks)
  half_t* bounce = (half_t*)smem2;
  float (*comb2)[512][2] = (float (*)[512][2])smem2;   // 32 KB <= 34816

  const int tid = threadIdx.x;
  const int wv = tid >> 6, ln = tid & 63;
  const int q = ln >> 4, l = ln & 15;
  const int b = blockIdx.x & 63;
  const int slab = blockIdx.x >> 6;
  const int i0 = slab * 128;
  const float bbs = *baff - 2.7725887f;   // fold 2^-4 scale into exp

  int rs3[3];   // the 3 remote slabs (static-indexed only)
  {
    int k = 0;
#pragma unroll
    for (int sl = 0; sl < 4; ++sl)
      if (sl != slab) rs3[k++] = sl;
  }

  // ================= P1: A-prep (block-local) =================
  v8h af[4];
  {
    const int row = wv * 16 + l;                    // local row 0..127
    const size_t xr = ((size_t)b * CN + i0 + row) * CD;
    const size_t pr = (size_t)(i0 + row) * CD;
    v8h xf[8];
#pragma unroll
    for (int kf = 0; kf < 8; ++kf) {
      const int c = kf * 32 + q * 8;
      float4 a0 = *(const float4*)&out_emb[xr + c];
      float4 a1 = *(const float4*)&out_emb[xr + c + 4];
      const float4 p0 = *(const float4*)&pos[pr + c];
      const float4 p1 = *(const float4*)&pos[pr + c + 4];
      a0.x += p0.x; a0.y += p0.y; a0.z += p0.z; a0.w += p0.w;
      a1.x += p1.x; a1.y += p1.y; a1.z += p1.z; a1.w += p1.w;
      v8h h;
      h[0] = (half_t)a0.x; h[1] = (half_t)a0.y;
      h[2] = (half_t)a0.z; h[3] = (half_t)a0.w;
      h[4] = (half_t)a1.x; h[5] = (half_t)a1.y;
      h[6] = (half_t)a1.z; h[7] = (half_t)a1.w;
      xf[kf] = h;
    }
    v4f acc[8] = {};
#pragma unroll
    for (int nn = 0; nn < 8; ++nn)
#pragma unroll
      for (int kf = 0; kf < 8; ++kf) {
        const v8h bw = *(const v8h*)&WaF[(size_t)((nn * 8 + kf) * 64 + ln) * 8];
        acc[nn] = __builtin_amdgcn_mfma_f32_16x16x32_f16(xf[kf], bw, acc[nn], 0, 0, 0);
      }
    // bounce: [row][col] stride 136 halfs (272B rows -> 16B-aligned reads,
    // write banks 2-way only)
#pragma unroll
    for (int nn = 0; nn < 8; ++nn)
#pragma unroll
      for (int g = 0; g < 4; ++g)
        bounce[(size_t)(wv * 16 + q * 4 + g) * 136 + nn * 16 + l] = (half_t)acc[nn][g];
  }
  __syncthreads();
#pragma unroll
  for (int ki = 0; ki < 4; ++ki)
    af[ki] = *(const v8h*)&bounce[(size_t)(wv * 16 + l) * 136 + ki * 32 + q * 8];
  __syncthreads();   // bounce free for B

  // ================= P2: B-prep + publish =================
  {
    const int flag = *flagp;
    const int row = wv * 16 + l;
    const int grow = b * CN + i0 + row;
    bool m;
    if (flag == 1)      m = ((const unsigned char*)maskp)[grow] != 0;
    else if (flag == 2) m = ((const float*)maskp)[grow] != 0.0f;
    else if (flag == 3) m = ((const long long*)maskp)[grow] != 0;
    else                m = ((const int*)maskp)[grow] != 0;
    const size_t xr = (size_t)grow * CD;
    v8h xf[8];
#pragma unroll
    for (int kf = 0; kf < 8; ++kf) {
      const int c = kf * 32 + q * 8;
      float4 a0, a1;
      if (m) {
        a0 = *(const float4*)&pad[c];
        a1 = *(const float4*)&pad[c + 4];
      } else {
        a0 = *(const float4*)&in_emb[xr + c];
        a1 = *(const float4*)&in_emb[xr + c + 4];
      }
      v8h h;
      h[0] = (half_t)a0.x; h[1] = (half_t)a0.y;
      h[2] = (half_t)a0.z; h[3] = (half_t)a0.w;
      h[4] = (half_t)a1.x; h[5] = (half_t)a1.y;
      h[6] = (half_t)a1.z; h[7] = (half_t)a1.w;
      xf[kf] = h;
    }
    v4f acc[8] = {};
#pragma unroll
    for (int nn = 0; nn < 8; ++nn)
#pragma unroll
      for (int kf = 0; kf < 8; ++kf) {
        const v8h bw = *(const v8h*)&WbF[(size_t)((nn * 8 + kf) * 64 + ln) * 8];
        acc[nn] = __builtin_amdgcn_mfma_f32_16x16x32_f16(xf[kf], bw, acc[nn], 0, 0, 0);
      }
#pragma unroll
    for (int nn = 0; nn < 8; ++nn)
#pragma unroll
      for (int g = 0; g < 4; ++g)
        bounce[(size_t)(wv * 16 + q * 4 + g) * 136 + nn * 16 + l] = (half_t)acc[nn][g];
  }
  __syncthreads();
  // coalesced sc0sc1 store of the B-slab to Bm (rows i0..i0+127)
  {
    const int row = tid >> 2, qt = tid & 3;
    half_t* dst = &Bm_h[((size_t)b * CN + i0 + row) * CE + qt * 32];
    const half_t* src = &bounce[(size_t)row * 136 + qt * 32];
#pragma unroll
    for (int j = 0; j < 4; ++j)
      llc_store4((v4f*)&dst[j * 8], *(const v4f*)&src[j * 8]);
  }
  __syncthreads();   // each wave drains vmcnt(0) before barrier => B at LLC
  if (tid == 0) llc_storef(&markers[(size_t)b * 4 + slab], 1.0f);

  // ================= P3: wait peers, then E-GEMM =================
  {
    const float* mk = &markers[(size_t)b * 4];
    float m0, m1, m2;
    while (true) {
      llc_load3f(&mk[rs3[0]], &mk[rs3[1]], &mk[rs3[2]], m0, m1, m2);
      if (m0 > 0.0f && m1 > 0.0f && m2 > 0.0f) break;
      __builtin_amdgcn_s_sleep(1);
    }
  }

  v4h eh[32];    // E[row = wv*16 + q*4+g][col = ct*16 + l]
  v4h ehT[32];   // E[row = wv*16 + l][col = ct*16 + q*4+g]
  {
    const half_t* Bbase = &Bm_h[(size_t)b * CN * CE];
#pragma unroll
    for (int ct = 0; ct < 32; ++ct) {
      v8h bf[4];
      const half_t* Brow = &Bbase[(size_t)(ct * 16 + l) * CE];
#pragma unroll
      for (int ki = 0; ki < 4; ++ki)
        bf[ki] = *(const v8h*)&Brow[ki * 32 + q * 8];
      v4f acc = {}, accT = {};
#pragma unroll
      for (int ki = 0; ki < 4; ++ki) {
        acc  = __builtin_amdgcn_mfma_f32_16x16x32_f16(af[ki], bf[ki], acc,  0, 0, 0);
        accT = __builtin_amdgcn_mfma_f32_16x16x32_f16(bf[ki], af[ki], accT, 0, 0, 0);
      }
#pragma unroll
      for (int g = 0; g < 4; ++g) {
        eh[ct][g]  = (half_t)__expf(acc[g]  + bbs);
        ehT[ct][g] = (half_t)__expf(accT[g] + bbs);
      }
    }
  }

  // ================= P4: sinkhorn (R2 artifact, unchanged) =================
  v4h ones;
  ones[0] = (half_t)1.0f; ones[1] = (half_t)1.0f;
  ones[2] = (half_t)1.0f; ones[3] = (half_t)1.0f;
  v4f rowacc0 = {}, rowacc1 = {};
#pragma unroll
  for (int ct = 0; ct < 32; ct += 2) {
    const v4f c0 = __builtin_amdgcn_mfma_f32_16x16x16f16(ones, eh[ct], (v4f){}, 0, 0, 0);
    const v4f c1 = __builtin_amdgcn_mfma_f32_16x16x16f16(ones, eh[ct + 1], (v4f){}, 0, 0, 0);
    if (ln < 16) {
      comb2[wv][ct * 16 + ln][0] = c0[0];
      comb2[wv][(ct + 1) * 16 + ln][0] = c1[0];
    }
    rowacc0 = __builtin_amdgcn_mfma_f32_16x16x16f16(ones, ehT[ct],     rowacc0, 0, 0, 0);
    rowacc1 = __builtin_amdgcn_mfma_f32_16x16x16f16(ones, ehT[ct + 1], rowacc1, 0, 0, 0);
  }
  const float rowtot = rowacc0[0] + rowacc1[0];
  float rv[4];
#pragma unroll
  for (int g = 0; g < 4; ++g)
    rv[g] = 1.0f / __shfl(rowtot, q * 4 + g);
  __syncthreads();

  {
    float S = 0.0f;
#pragma unroll
    for (int w = 0; w < 8; ++w) S += comb2[w][tid][0];
    QsL[tid] = S;
  }
  __syncthreads();
  if (tid < 128) {
    const v4f s4 = *(const v4f*)&QsL[tid * 4];
    v4f* pi4 = (v4f*)partInit + (size_t)b * 4 * 128;
    llc_store4(&pi4[slab * 128 + tid], s4);
    const v4f* q0 = &pi4[rs3[0] * 128 + tid];
    const v4f* q1 = &pi4[rs3[1] * 128 + tid];
    const v4f* q2 = &pi4[rs3[2] * 128 + tid];
    v4f r0, r1, r2;
    while (true) {
      llc_load3x4(q0, q1, q2, r0, r1, r2);
      if (allpos(r0) && allpos(r1) && allpos(r2)) break;
      __builtin_amdgcn_s_sleep(1);
    }
    const v4f T = s4 + r0 + r1 + r2;
    v4f ci;
    v4h w1v, w2v;
#pragma unroll
    for (int j = 0; j < 4; ++j) {
      ci[j] = 1.0f / T[j];
      w1v[j] = (half_t)(0.5f * ci[j]);
      w2v[j] = (half_t)1.0f;
    }
    csinv4[tid] = ci;
    *(v4h*)&wAll[tid * 4] = w1v;
    *(v4h*)&wAll[544 + tid * 4] = w2v;
  }
  __syncthreads();
  const float ci0 = ((const float*)csinv4)[tid];

  const half_t* wbase = (l == 1) ? (wAll + 544) : wAll;   // row0=w1, row1=w2
  float u_[4], uri[4];
  for (int t = 0; t < CIT; ++t) {
    __syncthreads();
    v4f Pe = {}, Po = {};
#pragma unroll
    for (int ct = 0; ct < 32; ct += 2) {
      const v4h wf0 = *(const v4h*)&wbase[ct * 16 + q * 4];
      const v4h wf1 = *(const v4h*)&wbase[(ct + 1) * 16 + q * 4];
      Pe = __builtin_amdgcn_mfma_f32_16x16x16f16(wf0, ehT[ct],     Pe, 0, 0, 0);
      Po = __builtin_amdgcn_mfma_f32_16x16x16f16(wf1, ehT[ct + 1], Po, 0, 0, 0);
    }
    const float Prow1 = Pe[0] + Po[0];
    const float Prow2 = Pe[1] + Po[1];
    v4h u_h, uri_h;
#pragma unroll
    for (int g = 0; g < 4; ++g) {
      const float p1 = __shfl(Prow1, q * 4 + g);
      const float p2 = __shfl(Prow2, q * 4 + g);
      u_[g] = 1.0f / (p1 + 0.5f * rv[g] * p2);
      uri[g] = u_[g] * rv[g];
      u_h[g] = (half_t)u_[g];
      uri_h[g] = (half_t)uri[g];
    }
    const v4h a2 = (l == 1) ? uri_h : u_h;
#pragma unroll
    for (int ct = 0; ct < 32; ++ct) {
      const v4f s = __builtin_amdgcn_mfma_f32_16x16x16f16(a2, eh[ct], (v4f){}, 0, 0, 0);
      if (ln < 16)
        *(float2*)&comb2[wv][ct * 16 + ln][0] = make_float2(s[0], s[1]);
    }
    __syncthreads();
    {
      float S1 = 0.0f, S2 = 0.0f;
#pragma unroll
      for (int w = 0; w < 8; ++w) {
        const float2 c2v = *(const float2*)&comb2[w][tid][0];
        S1 += c2v.x;
        S2 += c2v.y;
      }
      QsL[tid] = 0.5f * fmaf(ci0, S1, S2);
    }
    __syncthreads();
    if (tid < 128) {
      const v4f Q4 = *(const v4f*)&QsL[tid * 4];
      v4f* pr4 = (v4f*)partIter + (((size_t)t * 64 + b) * 4) * 128;
      llc_store4(&pr4[slab * 128 + tid], Q4);
      const v4f* q0 = &pr4[rs3[0] * 128 + tid];
      const v4f* q1 = &pr4[rs3[1] * 128 + tid];
      const v4f* q2 = &pr4[rs3[2] * 128 + tid];
      v4f r0, r1, r2;
      while (true) {
        llc_load3x4(q0, q1, q2, r0, r1, r2);
        if (allpos(r0) && allpos(r1) && allpos(r2)) break;
        __builtin_amdgcn_s_sleep(1);
      }
      const v4f tot = Q4 + r0 + r1 + r2;
      const v4f ci = csinv4[tid];
      v4h w1v, w2v;
#pragma unroll
      for (int j = 0; j < 4; ++j) {
        const float vv = 1.0f / tot[j];
        w1v[j] = (half_t)(0.5f * vv * ci[j]);
        w2v[j] = (half_t)vv;
        if (t == CIT - 1)
          w12[tid * 4 + j] = make_float2(0.5f * vv * ci[j], vv);
      }
      *(v4h*)&wAll[tid * 4] = w1v;
      *(v4h*)&wAll[544 + tid * 4] = w2v;
    }
  }

  // ---- finalize: P = E * u_i * v_j * (0.5*csinv_j + 0.5*rinv_i) ----
  __syncthreads();
  float* Pb = &P[((size_t)b * CN + i0 + wv * 16 + q * 4) * CN];
#pragma unroll
  for (int ct = 0; ct < 32; ++ct) {
    const float2 w = w12[ct * 16 + l];
    const float c1 = w.x;
    const float c2 = 0.5f * w.y;
#pragma unroll
    for (int g = 0; g < 4; ++g) {
      const float e = (float)eh[ct][g];
      Pb[(size_t)g * CN + ct * 16 + l] = e * fmaf(u_[g], c1, uri[g] * c2);
    }
  }
}

// ---------------------------------------------------------------------------
extern "C" void kernel_launch(void* const* d_in, const int* in_sizes, int n_in,
                              void* d_out, int out_size, void* d_ws, size_t ws_size,
                              hipStream_t stream) {
  const float* in_emb  = (const float*)d_in[0];
  const void*  mask    = d_in[1];
  const float* out_emb = (const float*)d_in[2];
  const float* pad     = (const float*)d_in[3];
  const float* pos     = (const float*)d_in[4];
  const float* W_a     = (const float*)d_in[5];
  const float* W_b     = (const float*)d_in[6];
  const float* w_aff   = (const float*)d_in[7];
  const float* b_aff   = (const float*)d_in[8];
  float* P = (float*)d_out;

  char* ws = (char*)d_ws;
  const size_t MB = 1024 * 1024;
  const size_t KB = 1024;
  half_t* Bm_h = (half_t*)ws;                              // 8 MB
  int*    flag = (int*)(ws + 8 * MB);                      // 4 B
  half_t* WaF  = (half_t*)(ws + 8 * MB + 16 * KB);         // 64 KB
  half_t* WbF  = (half_t*)(ws + 8 * MB + 80 * KB);         // 64 KB
  // contiguous sentinel region (precleared -1 by k0):
  float* partInit = (float*)(ws + 9 * MB);                 // 512 KB
  float* partIter = (float*)(ws + 9 * MB + 512 * KB);      // 10 MB
  float* markers  = (float*)(ws + 9 * MB + 512 * KB + 10 * MB);  // 1 KB

  const int nclear4 = (512 * 1024 + 10 * 1024 * 1024 + 1024) / 16;  // 688,192
  const int nclrblk = (nclear4 + 511) / 512;                        // 1345

  k0_init<<<dim3(18 + nclrblk), dim3(512), 0, stream>>>(
      mask, flag, W_a, W_b, w_aff, WaF, WbF, (float4*)partInit, nclear4);
  mega<<<dim3(256), dim3(512), 0, stream>>>(
      out_emb, pos, in_emb, pad, mask, flag, WaF, WbF, Bm_h,
      b_aff, P, partInit, partIter, markers);
}

// Round 7
// 305.903 us; speedup vs baseline: 1.2208x; 1.0011x over previous
//
#include <hip/hip_runtime.h>
#include <cstddef>

static constexpr int CB = 64;    // batch
static constexpr int CN = 512;   // nodes
static constexpr int CD = 256;   // node model dim
static constexpr int CE = 128;   // edge model dim
static constexpr int CIT = 20;   // sinkhorn iterations

typedef _Float16 half_t;
typedef __attribute__((ext_vector_type(8))) _Float16 v8h;
typedef __attribute__((ext_vector_type(4))) _Float16 v4h;
typedef __attribute__((ext_vector_type(4))) float v4f;

// ---------------------------------------------------------------------------
// LLC-coherent ops. NO fences / cache-maintenance (R1: release/acquire =>
// buffer_wbl2/inv storms). R6 VALIDATED the ordering primitive this round
// generalizes: sc0sc1 stores + per-wave s_waitcnt vmcnt(0) (at barrier) =>
// data at LLC BEFORE a subsequent sc0sc1 marker store => peers that observe
// the marker can read the payload with ordinary one-shot loads.
// Protocol ledger: R0 scalar-atomic payload-poll 160.7 | R2 16B payload-poll
// 158.4 | R3 +L2 channel 173 | R4 +XCD remap 190 | R6 marker-gated B handoff
// (once) PASSED. This round: marker-gated EVERY exchange; payload polling
// retired (its 1.5 TB/s poll traffic was congesting the LLC it waited on).
// Marker = one monotone float per (b,slab): -1 (k0 preclear, each launch) ->
// 1.0 (B ready) -> 2.0 (init sums) -> 3.0+t (iter t). Monotone => no
// per-iteration preclear, LLC-hot line, graph-replay safe.
// ---------------------------------------------------------------------------
__device__ __forceinline__ void llc_store4(v4f* p, v4f v) {
  asm volatile("global_store_dwordx4 %0, %1, off sc0 sc1"
               :: "v"(p), "v"(v) : "memory");
}
__device__ __forceinline__ void llc_storef(float* p, float v) {
  asm volatile("global_store_dword %0, %1, off sc0 sc1"
               :: "v"(p), "v"(v) : "memory");
}
__device__ __forceinline__ void llc_load3x4(const v4f* p0, const v4f* p1,
                                            const v4f* p2,
                                            v4f& a, v4f& b, v4f& c) {
  asm volatile("global_load_dwordx4 %0, %3, off sc0 sc1\n\t"
               "global_load_dwordx4 %1, %4, off sc0 sc1\n\t"
               "global_load_dwordx4 %2, %5, off sc0 sc1\n\t"
               "s_waitcnt vmcnt(0)"
               : "=&v"(a), "=&v"(b), "=&v"(c)
               : "v"(p0), "v"(p1), "v"(p2)
               : "memory");
}
__device__ __forceinline__ float llc_loadf(const float* p) {
  float v;
  asm volatile("global_load_dword %0, %1, off sc0 sc1\n\t"
               "s_waitcnt vmcnt(0)"
               : "=v"(v) : "v"(p) : "memory");
  return v;
}
// Narrow marker poll: lanes 0-2 of the calling wave each watch one remote
// slab's marker (12 B/round/wave, hot line); wave exits when all 3 passed.
__device__ __forceinline__ void wait_marker(const float* mk, int rsl, int ln,
                                            float target) {
  while (true) {
    float f = 1e30f;
    if (ln < 3) f = llc_loadf(&mk[rsl]);
    if (__all(f > target)) break;
    __builtin_amdgcn_s_sleep(1);
  }
}

// ---------------------------------------------------------------------------
// k0: block 0 = mask dtype detect; block 1 = clear the 256 markers to -1
// (1 KB — the 10.5 MB payload preclear is gone, markers gate validity now);
// 2..9 = W_a -> fp16 B-fragments (w_aff folded); 10..17 = W_b.
// flag: 0=int32, 1=uint8(bool), 2=float32, 3=int64
// ---------------------------------------------------------------------------
__global__ __launch_bounds__(512) void k0_init(
    const void* __restrict__ mask, int* __restrict__ flag,
    const float* __restrict__ W_a, const float* __restrict__ W_b,
    const float* __restrict__ w_aff,
    half_t* __restrict__ WaF, half_t* __restrict__ WbF,
    float4* __restrict__ markers4) {
  const int tid = threadIdx.x;
  const int blk = blockIdx.x;
  if (blk == 1) {
    if (tid < CB * 4 / 4)   // 64 float4 = 256 marker floats
      markers4[tid] = make_float4(-1.0f, -1.0f, -1.0f, -1.0f);
    return;
  }
  if (blk >= 2) {
    const bool is_a = (blk < 10);
    const float* W = is_a ? W_a : W_b;
    half_t* WF = is_a ? WaF : WbF;
    const int e = (blk - (is_a ? 2 : 10)) * 512 + tid;   // 0..4095
    const int fB = e >> 6, lane = e & 63;
    const int nn = fB >> 3, kf = fB & 7;
    const int col = nn * 16 + (lane & 15);
    const int q = lane >> 4;
    const float scale = is_a ? w_aff[col] : 1.0f;
    v8h hv;
#pragma unroll
    for (int j = 0; j < 8; ++j) {
      const int k = kf * 32 + q * 8 + j;
      hv[j] = (half_t)(W[(size_t)k * CE + col] * scale);
    }
    *(v8h*)&WF[(size_t)e * 8] = hv;
    return;
  }
  // blk == 0: mask dtype detection over first 32768 bytes
  __shared__ int cnt[5];
  if (tid < 5) cnt[tid] = 0;
  __syncthreads();
  const unsigned char* p = (const unsigned char*)mask;
  int l0 = 0, l1 = 0, l2 = 0, l3 = 0, l4 = 0;
  const int base = tid * 64;
  for (int k = 0; k < 64; ++k) {
    const int off = base + k;
    if (p[off]) {
      const int m4 = off & 3;
      if (m4 == 1) l1++;
      else if (m4 == 2) l2++;
      else if (m4 == 3) l3++;
      else if ((off & 7) == 4) l4++;
      else l0++;
    }
  }
  if (l0) atomicAdd(&cnt[0], 1);
  if (l1) atomicAdd(&cnt[1], 1);
  if (l2) atomicAdd(&cnt[2], 1);
  if (l3) atomicAdd(&cnt[3], 1);
  if (l4) atomicAdd(&cnt[4], 1);
  __syncthreads();
  if (tid == 0) {
    int f;
    if (cnt[1]) f = 1;
    else if (cnt[2] || cnt[3]) f = 2;
    else if (cnt[4]) f = 0;
    else if (cnt[0]) f = 3;
    else f = 1;
    *flag = f;
  }
}

// ---------------------------------------------------------------------------
// mega: prep + sinkhorn in ONE dispatch (R6-validated structure, 193 µs).
// Block = (b, slab). P1 A-prep (block-local, LDS bounce). P2 B-prep ->
// sc0sc1 stores to Bm -> drain -> marker=1. P3 wait peers' markers -> E-GEMM
// with plain cached B reads. P4 sinkhorn with marker-gated exchanges
// (init marker=2, iter t marker=3+t) — payload polling retired.
// Grid 256 = 1 block/CU => co-residency.
// ---------------------------------------------------------------------------
__global__ __launch_bounds__(512, 2) void mega(
    const float* __restrict__ out_emb, const float* __restrict__ pos,
    const float* __restrict__ in_emb, const float* __restrict__ pad,
    const void* __restrict__ maskp, const int* __restrict__ flagp,
    const half_t* __restrict__ WaF, const half_t* __restrict__ WbF,
    half_t* __restrict__ Bm_h,
    const float* __restrict__ baff, float* __restrict__ P,
    float* __restrict__ partInit, float* __restrict__ partIter,
    float* __restrict__ markers) {
  // smem2: A/B bounce [128][136] halfs (34816 B), later aliased as comb2
  __shared__ __align__(16) char smem2[34816];
  __shared__ __align__(16) float2 w12[512];    // {0.5*v*csinv, v} (finalize)
  __shared__ __align__(16) float QsL[512];     // per-col publish staging
  __shared__ __align__(16) v4f csinv4[128];    // 1/colsum, 4 cols per slot
  __shared__ __align__(16) half_t wAll[1056];  // w1 @0, w2 @544 (+16 banks)
  half_t* bounce = (half_t*)smem2;
  float (*comb2)[512][2] = (float (*)[512][2])smem2;   // 32 KB <= 34816

  const int tid = threadIdx.x;
  const int wv = tid >> 6, ln = tid & 63;
  const int q = ln >> 4, l = ln & 15;
  const int b = blockIdx.x & 63;
  const int slab = blockIdx.x >> 6;
  const int i0 = slab * 128;
  const float bbs = *baff - 2.7725887f;   // fold 2^-4 scale into exp

  int rs3[3];   // the 3 remote slabs (static-indexed only)
  {
    int k = 0;
#pragma unroll
    for (int sl = 0; sl < 4; ++sl)
      if (sl != slab) rs3[k++] = sl;
  }
  // remote slab watched by lane ln (<3) during marker polls
  const int rsl = (ln < 3) ? (ln + (ln >= slab ? 1 : 0)) : 0;
  float* mk = &markers[(size_t)b * 4];

  // ================= P1: A-prep (block-local) =================
  v8h af[4];
  {
    const int row = wv * 16 + l;                    // local row 0..127
    const size_t xr = ((size_t)b * CN + i0 + row) * CD;
    const size_t pr = (size_t)(i0 + row) * CD;
    v8h xf[8];
#pragma unroll
    for (int kf = 0; kf < 8; ++kf) {
      const int c = kf * 32 + q * 8;
      float4 a0 = *(const float4*)&out_emb[xr + c];
      float4 a1 = *(const float4*)&out_emb[xr + c + 4];
      const float4 p0 = *(const float4*)&pos[pr + c];
      const float4 p1 = *(const float4*)&pos[pr + c + 4];
      a0.x += p0.x; a0.y += p0.y; a0.z += p0.z; a0.w += p0.w;
      a1.x += p1.x; a1.y += p1.y; a1.z += p1.z; a1.w += p1.w;
      v8h h;
      h[0] = (half_t)a0.x; h[1] = (half_t)a0.y;
      h[2] = (half_t)a0.z; h[3] = (half_t)a0.w;
      h[4] = (half_t)a1.x; h[5] = (half_t)a1.y;
      h[6] = (half_t)a1.z; h[7] = (half_t)a1.w;
      xf[kf] = h;
    }
    v4f acc[8] = {};
#pragma unroll
    for (int nn = 0; nn < 8; ++nn)
#pragma unroll
      for (int kf = 0; kf < 8; ++kf) {
        const v8h bw = *(const v8h*)&WaF[(size_t)((nn * 8 + kf) * 64 + ln) * 8];
        acc[nn] = __builtin_amdgcn_mfma_f32_16x16x32_f16(xf[kf], bw, acc[nn], 0, 0, 0);
      }
#pragma unroll
    for (int nn = 0; nn < 8; ++nn)
#pragma unroll
      for (int g = 0; g < 4; ++g)
        bounce[(size_t)(wv * 16 + q * 4 + g) * 136 + nn * 16 + l] = (half_t)acc[nn][g];
  }
  __syncthreads();
#pragma unroll
  for (int ki = 0; ki < 4; ++ki)
    af[ki] = *(const v8h*)&bounce[(size_t)(wv * 16 + l) * 136 + ki * 32 + q * 8];
  __syncthreads();   // bounce free for B

  // ================= P2: B-prep + publish =================
  {
    const int flag = *flagp;
    const int row = wv * 16 + l;
    const int grow = b * CN + i0 + row;
    bool m;
    if (flag == 1)      m = ((const unsigned char*)maskp)[grow] != 0;
    else if (flag == 2) m = ((const float*)maskp)[grow] != 0.0f;
    else if (flag == 3) m = ((const long long*)maskp)[grow] != 0;
    else                m = ((const int*)maskp)[grow] != 0;
    const size_t xr = (size_t)grow * CD;
    v8h xf[8];
#pragma unroll
    for (int kf = 0; kf < 8; ++kf) {
      const int c = kf * 32 + q * 8;
      float4 a0, a1;
      if (m) {
        a0 = *(const float4*)&pad[c];
        a1 = *(const float4*)&pad[c + 4];
      } else {
        a0 = *(const float4*)&in_emb[xr + c];
        a1 = *(const float4*)&in_emb[xr + c + 4];
      }
      v8h h;
      h[0] = (half_t)a0.x; h[1] = (half_t)a0.y;
      h[2] = (half_t)a0.z; h[3] = (half_t)a0.w;
      h[4] = (half_t)a1.x; h[5] = (half_t)a1.y;
      h[6] = (half_t)a1.z; h[7] = (half_t)a1.w;
      xf[kf] = h;
    }
    v4f acc[8] = {};
#pragma unroll
    for (int nn = 0; nn < 8; ++nn)
#pragma unroll
      for (int kf = 0; kf < 8; ++kf) {
        const v8h bw = *(const v8h*)&WbF[(size_t)((nn * 8 + kf) * 64 + ln) * 8];
        acc[nn] = __builtin_amdgcn_mfma_f32_16x16x32_f16(xf[kf], bw, acc[nn], 0, 0, 0);
      }
#pragma unroll
    for (int nn = 0; nn < 8; ++nn)
#pragma unroll
      for (int g = 0; g < 4; ++g)
        bounce[(size_t)(wv * 16 + q * 4 + g) * 136 + nn * 16 + l] = (half_t)acc[nn][g];
  }
  __syncthreads();
  // coalesced sc0sc1 store of the B-slab to Bm (rows i0..i0+127)
  {
    const int row = tid >> 2, qt = tid & 3;
    half_t* dst = &Bm_h[((size_t)b * CN + i0 + row) * CE + qt * 32];
    const half_t* src = &bounce[(size_t)row * 136 + qt * 32];
#pragma unroll
    for (int j = 0; j < 4; ++j)
      llc_store4((v4f*)&dst[j * 8], *(const v4f*)&src[j * 8]);
    asm volatile("s_waitcnt vmcnt(0)" ::: "memory");
  }
  __syncthreads();   // all waves drained => B-slab fully at LLC
  if (tid == 0) llc_storef(&mk[slab], 1.0f);

  // ================= P3: wait peers (markers), then E-GEMM =================
  wait_marker(mk, rsl, ln, 0.5f);   // per-wave, 3 scalar loads/round

  v4h eh[32];    // E[row = wv*16 + q*4+g][col = ct*16 + l]
  v4h ehT[32];   // E[row = wv*16 + l][col = ct*16 + q*4+g]
  {
    const half_t* Bbase = &Bm_h[(size_t)b * CN * CE];
#pragma unroll
    for (int ct = 0; ct < 32; ++ct) {
      v8h bf[4];
      const half_t* Brow = &Bbase[(size_t)(ct * 16 + l) * CE];
#pragma unroll
      for (int ki = 0; ki < 4; ++ki)
        bf[ki] = *(const v8h*)&Brow[ki * 32 + q * 8];
      v4f acc = {}, accT = {};
#pragma unroll
      for (int ki = 0; ki < 4; ++ki) {
        acc  = __builtin_amdgcn_mfma_f32_16x16x32_f16(af[ki], bf[ki], acc,  0, 0, 0);
        accT = __builtin_amdgcn_mfma_f32_16x16x32_f16(bf[ki], af[ki], accT, 0, 0, 0);
      }
#pragma unroll
      for (int g = 0; g < 4; ++g) {
        eh[ct][g]  = (half_t)__expf(acc[g]  + bbs);
        ehT[ct][g] = (half_t)__expf(accT[g] + bbs);
      }
    }
  }

  // ================= P4: sinkhorn =================
  v4h ones;
  ones[0] = (half_t)1.0f; ones[1] = (half_t)1.0f;
  ones[2] = (half_t)1.0f; ones[3] = (half_t)1.0f;
  v4f rowacc0 = {}, rowacc1 = {};
#pragma unroll
  for (int ct = 0; ct < 32; ct += 2) {
    const v4f c0 = __builtin_amdgcn_mfma_f32_16x16x16f16(ones, eh[ct], (v4f){}, 0, 0, 0);
    const v4f c1 = __builtin_amdgcn_mfma_f32_16x16x16f16(ones, eh[ct + 1], (v4f){}, 0, 0, 0);
    if (ln < 16) {
      comb2[wv][ct * 16 + ln][0] = c0[0];
      comb2[wv][(ct + 1) * 16 + ln][0] = c1[0];
    }
    rowacc0 = __builtin_amdgcn_mfma_f32_16x16x16f16(ones, ehT[ct],     rowacc0, 0, 0, 0);
    rowacc1 = __builtin_amdgcn_mfma_f32_16x16x16f16(ones, ehT[ct + 1], rowacc1, 0, 0, 0);
  }
  const float rowtot = rowacc0[0] + rowacc1[0];
  float rv[4];
#pragma unroll
  for (int g = 0; g < 4; ++g)
    rv[g] = 1.0f / __shfl(rowtot, q * 4 + g);
  __syncthreads();

  // ---- init exchange: marker-gated (marker 2.0) ----
  {
    float S = 0.0f;
#pragma unroll
    for (int w = 0; w < 8; ++w) S += comb2[w][tid][0];
    QsL[tid] = S;
  }
  __syncthreads();
  v4f s4 = {};
  if (tid < 128) {
    s4 = *(const v4f*)&QsL[tid * 4];
    v4f* pi4 = (v4f*)partInit + (size_t)b * 4 * 128;
    llc_store4(&pi4[slab * 128 + tid], s4);
    asm volatile("s_waitcnt vmcnt(0)" ::: "memory");
  }
  __syncthreads();   // payload fully at LLC before marker
  if (tid < 128) {
    if (tid == 0) llc_storef(&mk[slab], 2.0f);
    wait_marker(mk, rsl, ln, 1.5f);
    v4f* pi4 = (v4f*)partInit + (size_t)b * 4 * 128;
    v4f r0, r1, r2;
    llc_load3x4(&pi4[rs3[0] * 128 + tid], &pi4[rs3[1] * 128 + tid],
                &pi4[rs3[2] * 128 + tid], r0, r1, r2);
    const v4f T = s4 + r0 + r1 + r2;
    v4f ci;
    v4h w1v, w2v;
#pragma unroll
    for (int j = 0; j < 4; ++j) {
      ci[j] = 1.0f / T[j];
      w1v[j] = (half_t)(0.5f * ci[j]);
      w2v[j] = (half_t)1.0f;
    }
    csinv4[tid] = ci;
    *(v4h*)&wAll[tid * 4] = w1v;
    *(v4h*)&wAll[544 + tid * 4] = w2v;
  }
  __syncthreads();
  const float ci0 = ((const float*)csinv4)[tid];

  // ---- 20 iterations, marker-gated exchange (marker 3.0+t) ----
  const half_t* wbase = (l == 1) ? (wAll + 544) : wAll;   // row0=w1, row1=w2
  float u_[4], uri[4];
  for (int t = 0; t < CIT; ++t) {
    __syncthreads();
    v4f Pe = {}, Po = {};
#pragma unroll
    for (int ct = 0; ct < 32; ct += 2) {
      const v4h wf0 = *(const v4h*)&wbase[ct * 16 + q * 4];
      const v4h wf1 = *(const v4h*)&wbase[(ct + 1) * 16 + q * 4];
      Pe = __builtin_amdgcn_mfma_f32_16x16x16f16(wf0, ehT[ct],     Pe, 0, 0, 0);
      Po = __builtin_amdgcn_mfma_f32_16x16x16f16(wf1, ehT[ct + 1], Po, 0, 0, 0);
    }
    const float Prow1 = Pe[0] + Po[0];
    const float Prow2 = Pe[1] + Po[1];
    v4h u_h, uri_h;
#pragma unroll
    for (int g = 0; g < 4; ++g) {
      const float p1 = __shfl(Prow1, q * 4 + g);
      const float p2 = __shfl(Prow2, q * 4 + g);
      u_[g] = 1.0f / (p1 + 0.5f * rv[g] * p2);
      uri[g] = u_[g] * rv[g];
      u_h[g] = (half_t)u_[g];
      uri_h[g] = (half_t)uri[g];
    }
    const v4h a2 = (l == 1) ? uri_h : u_h;
#pragma unroll
    for (int ct = 0; ct < 32; ++ct) {
      const v4f s = __builtin_amdgcn_mfma_f32_16x16x16f16(a2, eh[ct], (v4f){}, 0, 0, 0);
      if (ln < 16)
        *(float2*)&comb2[wv][ct * 16 + ln][0] = make_float2(s[0], s[1]);
    }
    __syncthreads();
    {
      float S1 = 0.0f, S2 = 0.0f;
#pragma unroll
      for (int w = 0; w < 8; ++w) {
        const float2 c2v = *(const float2*)&comb2[w][tid][0];
        S1 += c2v.x;
        S2 += c2v.y;
      }
      QsL[tid] = 0.5f * fmaf(ci0, S1, S2);
    }
    __syncthreads();
    v4f Q4 = {};
    if (tid < 128) {
      Q4 = *(const v4f*)&QsL[tid * 4];
      v4f* pr4 = (v4f*)partIter + (((size_t)t * 64 + b) * 4) * 128;
      llc_store4(&pr4[slab * 128 + tid], Q4);
      asm volatile("s_waitcnt vmcnt(0)" ::: "memory");
    }
    __syncthreads();   // payload fully at LLC before marker
    if (tid < 128) {
      if (tid == 0) llc_storef(&mk[slab], 3.0f + (float)t);
      wait_marker(mk, rsl, ln, 2.5f + (float)t);
      v4f* pr4 = (v4f*)partIter + (((size_t)t * 64 + b) * 4) * 128;
      v4f r0, r1, r2;
      llc_load3x4(&pr4[rs3[0] * 128 + tid], &pr4[rs3[1] * 128 + tid],
                  &pr4[rs3[2] * 128 + tid], r0, r1, r2);
      const v4f tot = Q4 + r0 + r1 + r2;
      const v4f ci = csinv4[tid];
      v4h w1v, w2v;
#pragma unroll
      for (int j = 0; j < 4; ++j) {
        const float vv = 1.0f / tot[j];
        w1v[j] = (half_t)(0.5f * vv * ci[j]);
        w2v[j] = (half_t)vv;
        if (t == CIT - 1)
          w12[tid * 4 + j] = make_float2(0.5f * vv * ci[j], vv);
      }
      *(v4h*)&wAll[tid * 4] = w1v;
      *(v4h*)&wAll[544 + tid * 4] = w2v;
    }
  }

  // ---- finalize: P = E * u_i * v_j * (0.5*csinv_j + 0.5*rinv_i) ----
  __syncthreads();
  float* Pb = &P[((size_t)b * CN + i0 + wv * 16 + q * 4) * CN];
#pragma unroll
  for (int ct = 0; ct < 32; ++ct) {
    const float2 w = w12[ct * 16 + l];
    const float c1 = w.x;
    const float c2 = 0.5f * w.y;
#pragma unroll
    for (int g = 0; g < 4; ++g) {
      const float e = (float)eh[ct][g];
      Pb[(size_t)g * CN + ct * 16 + l] = e * fmaf(u_[g], c1, uri[g] * c2);
    }
  }
}

// ---------------------------------------------------------------------------
extern "C" void kernel_launch(void* const* d_in, const int* in_sizes, int n_in,
                              void* d_out, int out_size, void* d_ws, size_t ws_size,
                              hipStream_t stream) {
  const float* in_emb  = (const float*)d_in[0];
  const void*  mask    = d_in[1];
  const float* out_emb = (const float*)d_in[2];
  const float* pad     = (const float*)d_in[3];
  const float* pos     = (const float*)d_in[4];
  const float* W_a     = (const float*)d_in[5];
  const float* W_b     = (const float*)d_in[6];
  const float* w_aff   = (const float*)d_in[7];
  const float* b_aff   = (const float*)d_in[8];
  float* P = (float*)d_out;

  char* ws = (char*)d_ws;
  const size_t MB = 1024 * 1024;
  const size_t KB = 1024;
  half_t* Bm_h = (half_t*)ws;                              // 8 MB
  int*    flag = (int*)(ws + 8 * MB);                      // 4 B
  half_t* WaF  = (half_t*)(ws + 8 * MB + 16 * KB);         // 64 KB
  half_t* WbF  = (half_t*)(ws + 8 * MB + 80 * KB);         // 64 KB
  float* partInit = (float*)(ws + 9 * MB);                 // 512 KB (no preclear)
  float* partIter = (float*)(ws + 9 * MB + 512 * KB);      // 10 MB (no preclear)
  float* markers  = (float*)(ws + 9 * MB + 512 * KB + 10 * MB);  // 1 KB (precleared -1)

  k0_init<<<dim3(18), dim3(512), 0, stream>>>(
      mask, flag, W_a, W_b, w_aff, WaF, WbF, (float4*)markers);
  mega<<<dim3(256), dim3(512), 0, stream>>>(
      out_emb, pos, in_emb, pad, mask, flag, WaF, WbF, Bm_h,
      b_aff, P, partInit, partIter, markers);
}